// Round 6
// baseline (2174.124 us; speedup 1.0000x reference)
//
#include <hip/hip_runtime.h>
#include <hip/hip_bf16.h>
#include <stdint.h>

// ---------------------------------------------------------------------------
// CapsuleNet forward, MI355X gfx950.  Round 6:
//  * conv2: LDS-staged (m97-style) 128x128 tile, BK=64, global_load_lds for B,
//    S=8 K-split w/ fp32 atomics into transposed h2t[b][co][pos].
//  * routing: W-stationary multi-pass (5 einsum passes w/ W-tile in LDS,
//    2 softmax, 3 squash) -- W traffic 1.5GB -> ~15MB.
//  * decoder: weight-stationary dec2/dec3 (weights in LDS, loop over batch).
//  * ws total 72.5 MB (known ws_size >= 74.1 MB); heavy region overlaying.
// ---------------------------------------------------------------------------

typedef short short8 __attribute__((ext_vector_type(8)));
typedef unsigned short u16x8 __attribute__((ext_vector_type(8)));
typedef float f32x4  __attribute__((ext_vector_type(4)));

__device__ inline float bf2f(unsigned short u) {
    unsigned int v = ((unsigned int)u) << 16;
    float f;
    __builtin_memcpy(&f, &v, 4);
    return f;
}
__device__ inline unsigned short f2bf(float f) {
    __hip_bfloat16 h = __float2bfloat16(f);
    unsigned short u;
    __builtin_memcpy(&u, &h, 2);
    return u;
}
__device__ inline float clampf(float x, float b) {   // scrubs NaN -> -b
    return fminf(fmaxf(x, -b), b);
}
__device__ inline float rdf(const void* p, size_t i, int f) {
    return f ? ((const float*)p)[i] : bf2f(((const unsigned short*)p)[i]);
}
__device__ inline void gload_lds16(const unsigned short* g, unsigned short* l) {
    __builtin_amdgcn_global_load_lds(
        (const __attribute__((address_space(1))) void*)g,
        (__attribute__((address_space(3))) void*)l, 16, 0, 0);
}

// ---------------------------------------------------------------------------
__global__ void k_detect(const void* w, int* flag) {
    int lane = threadIdx.x;                       // 64 threads
    const unsigned short* u = (const unsigned short*)w;
    int cnt = 0;
#pragma unroll
    for (int j = 0; j < 4; ++j) {
        float v = fabsf(bf2f(u[lane * 4 + j]));
        if (v > 100.f) cnt++;
    }
#pragma unroll
    for (int off = 32; off; off >>= 1) cnt += __shfl_xor(cnt, off);
    if (lane == 0) flag[0] = (cnt >= 4) ? 1 : 0;
}

__global__ void k_zero(float* __restrict__ p) {    // grid*256 f32x4
    int i = blockIdx.x * 256 + threadIdx.x;
    ((f32x4*)p)[i] = (f32x4){0.f, 0.f, 0.f, 0.f};
}

// ---------------------------------------------------------------------------
__global__ void k_repack_w1(const void* __restrict__ w,
                            unsigned short* __restrict__ B1p,
                            const int* __restrict__ flagp) {
    int f = *flagp;
    int idx = blockIdx.x * 256 + threadIdx.x;      // 256*96
    int co = idx / 96, k = idx - co * 96;
    B1p[idx] = (k < 81) ? f2bf(rdf(w, (size_t)co * 81 + k, f)) : (unsigned short)0;
}

// pconv_w [co][ci][81] -> Bp3[t][kc][co][cin] bf16 (kc=ci>>6, cin=ci&63).
__global__ __launch_bounds__(256) void k_repack_w2(
        const void* __restrict__ w, unsigned short* __restrict__ Bp,
        const int* __restrict__ flagp) {
    __shared__ unsigned short wl[20736];           // [ci][t], 41.5 KB
    int f = *flagp;
    int co = blockIdx.x;
    int tid = threadIdx.x;
    size_t base = (size_t)co * 20736;
    for (int i = tid; i < 20736; i += 256)
        wl[i] = f2bf(rdf(w, base + i, f));         // wl[ci*81+t]
    __syncthreads();
    for (int idx = tid; idx < 20736; idx += 256) {
        int t = idx >> 8, ci = idx & 255;          // 81*256 = 20736
        if (t < 81) {
            int kc = ci >> 6, cin = ci & 63;
            Bp[(size_t)(t * 4 + kc) * 16384 + co * 64 + cin] = wl[ci * 81 + t];
        }
    }
}

// ---------------------------------------------------------------------------
// conv1: C[102400,256] = im2col(x) * B1p^T, 128x128 tiles, x staged in LDS.
__global__ __launch_bounds__(256) void k_conv1(
        const void* __restrict__ x,
        const unsigned short* __restrict__ B1p,
        const void* __restrict__ bias,
        unsigned short* __restrict__ h1p,
        const int* __restrict__ flagp) {
    __shared__ unsigned short xl[1568];            // up to 2 images, bf16
    __shared__ int offt[96];
    int f = *flagp;
    int tid = threadIdx.x;
    if (tid < 96) offt[tid] = (tid < 81) ? (tid / 9) * 28 + (tid % 9) : 0;

    int mblk = blockIdx.x * 128;
    int bfirst = mblk / 400;
    int blast = (mblk + 127) / 400;
    int nload = (blast - bfirst + 1) * 784;
    for (int i = tid; i < nload; i += 256)
        xl[i] = f2bf(rdf(x, (size_t)bfirst * 784 + i, f));
    __syncthreads();

    int wave = tid >> 6, lane = tid & 63;
    int wr = wave >> 1, wc = wave & 1;
    int mbase = mblk + wr * 64;
    int nbase = blockIdx.y * 128 + wc * 64;
    int l15 = lane & 15, l4 = lane >> 4;

    int lbase[4];
#pragma unroll
    for (int mt = 0; mt < 4; ++mt) {
        int m = mbase + mt * 16 + l15;
        int img = m / 400 - bfirst, pos = m % 400;
        lbase[mt] = img * 784 + (pos / 20) * 28 + (pos % 20);
    }

    f32x4 acc[4][4];
#pragma unroll
    for (int mt = 0; mt < 4; ++mt)
#pragma unroll
        for (int nt = 0; nt < 4; ++nt)
            acc[mt][nt] = (f32x4){0.f, 0.f, 0.f, 0.f};

#pragma unroll
    for (int kc = 0; kc < 3; ++kc) {
        int kbase = kc * 32 + l4 * 8;
        short8 af[4], bfr[4];
#pragma unroll
        for (int mt = 0; mt < 4; ++mt)
#pragma unroll
            for (int j = 0; j < 8; ++j) {
                int k = kbase + j;
                af[mt][j] = (k < 81) ? (short)xl[lbase[mt] + offt[k]] : (short)0;
            }
#pragma unroll
        for (int nt = 0; nt < 4; ++nt)
            bfr[nt] = *(const short8*)(B1p + (size_t)(nbase + nt * 16 + l15) * 96 + kbase);
#pragma unroll
        for (int mt = 0; mt < 4; ++mt)
#pragma unroll
            for (int nt = 0; nt < 4; ++nt)
                acc[mt][nt] = __builtin_amdgcn_mfma_f32_16x16x32_bf16(
                    af[mt], bfr[nt], acc[mt][nt], 0, 0, 0);
    }

#pragma unroll
    for (int mt = 0; mt < 4; ++mt)
#pragma unroll
        for (int nt = 0; nt < 4; ++nt) {
            int col = nbase + nt * 16 + l15;
            float bv = rdf(bias, col, f);
#pragma unroll
            for (int r = 0; r < 4; ++r) {
                int row = mbase + mt * 16 + l4 * 4 + r;
                h1p[(size_t)row * 256 + col] = f2bf(clampf(acc[mt][nt][r] + bv, 1024.f));
            }
        }
}

// ---------------------------------------------------------------------------
// conv2: LDS-staged implicit-im2col GEMM. 128x128 tile, BK=64, S=8 tap split.
// A: manual load+ds_write (scattered rows). B: global_load_lds from Bp3.
// Output: atomicAdd fp32 into h2t[b][co][pos] (transposed for caps).
__global__ __launch_bounds__(256) void k_conv2(
        const unsigned short* __restrict__ h1p,
        const unsigned short* __restrict__ Bp,
        float* __restrict__ h2t) {
    __shared__ unsigned short As[8192];            // [128][64]
    __shared__ unsigned short Bs[8192];            // [128][64]
    int tid = threadIdx.x;
    int wave = tid >> 6, lane = tid & 63;
    int wr = wave >> 1, wc = wave & 1;
    int mbase = blockIdx.x * 128;
    int nbase = blockIdx.y * 128;
    int s = blockIdx.z;
    int t0 = (81 * s) >> 3, t1 = (81 * (s + 1)) >> 3;
    int l15 = lane & 15, l4 = lane >> 4;

    // A staging mapping: thread -> (row, half)
    int ar = tid & 127, ah = tid >> 7;
    {
        // precompute global row base for this thread's staging row
    }
    int am = mbase + ar;
    int abb = am / 36, apos = am - abb * 36;
    int ay = apos / 6, ax = apos - ay * 6;
    const unsigned short* agp = h1p + (size_t)(abb * 400 + ay * 40 + ax * 2) * 256 + ah * 32;
    unsigned short* alp = As + ar * 64 + ah * 32;
    unsigned short* blw = Bs + wave * 2048;        // this wave's 32 rows

    // fragment LDS offsets
    int arow[4], brow[4];
#pragma unroll
    for (int mt = 0; mt < 4; ++mt) arow[mt] = (wr * 64 + mt * 16 + l15) * 64;
#pragma unroll
    for (int nt = 0; nt < 4; ++nt) brow[nt] = (wc * 64 + nt * 16 + l15) * 64;

    f32x4 acc[4][4];
#pragma unroll
    for (int mt = 0; mt < 4; ++mt)
#pragma unroll
        for (int nt = 0; nt < 4; ++nt)
            acc[mt][nt] = (f32x4){0.f, 0.f, 0.f, 0.f};

    for (int t = t0; t < t1; ++t) {
        int ky = t / 9, kx = t - ky * 9;
        int tadd = (ky * 20 + kx) * 256;
        for (int kc = 0; kc < 4; ++kc) {
            // ---- stage B via global_load_lds (4 x 1KB per wave)
            const unsigned short* bsrc =
                Bp + (((size_t)(t * 4 + kc) * 256 + nbase + wave * 32) << 6) + lane * 8;
            gload_lds16(bsrc,            blw);
            gload_lds16(bsrc + (8 << 6), blw + 512);
            gload_lds16(bsrc + (16 << 6), blw + 1024);
            gload_lds16(bsrc + (24 << 6), blw + 1536);
            // ---- stage A: 4 x 16B per thread
            const unsigned short* ag = agp + tadd + kc * 64;
            uint4 a0 = *(const uint4*)(ag);
            uint4 a1 = *(const uint4*)(ag + 8);
            uint4 a2 = *(const uint4*)(ag + 16);
            uint4 a3 = *(const uint4*)(ag + 24);
            *(uint4*)(alp)      = a0;
            *(uint4*)(alp + 8)  = a1;
            *(uint4*)(alp + 16) = a2;
            *(uint4*)(alp + 24) = a3;
            __syncthreads();
            // ---- compute 2 k-steps of 32
#pragma unroll
            for (int kk = 0; kk < 2; ++kk) {
                int ko = kk * 32 + l4 * 8;
                short8 af[4], bfr[4];
#pragma unroll
                for (int mt = 0; mt < 4; ++mt)
                    af[mt] = *(const short8*)(As + arow[mt] + ko);
#pragma unroll
                for (int nt = 0; nt < 4; ++nt)
                    bfr[nt] = *(const short8*)(Bs + brow[nt] + ko);
#pragma unroll
                for (int mt = 0; mt < 4; ++mt)
#pragma unroll
                    for (int nt = 0; nt < 4; ++nt)
                        acc[mt][nt] = __builtin_amdgcn_mfma_f32_16x16x32_bf16(
                            af[mt], bfr[nt], acc[mt][nt], 0, 0, 0);
            }
            __syncthreads();
        }
    }

#pragma unroll
    for (int mt = 0; mt < 4; ++mt)
#pragma unroll
        for (int nt = 0; nt < 4; ++nt) {
            int co = nbase + wc * 64 + nt * 16 + l15;
#pragma unroll
            for (int r = 0; r < 4; ++r) {
                int mm = mbase + wr * 64 + mt * 16 + l4 * 4 + r;
                int bb2 = mm / 36, pp = mm - bb2 * 36;
                atomicAdd(&h2t[(size_t)bb2 * 9216 + co * 36 + pp], acc[mt][nt][r]);
            }
        }
}

// ---------------------------------------------------------------------------
// +bias, squash -> caps bf16. h2t layout makes reads fully coalesced.
__global__ void k_caps(const float* __restrict__ h2t,
                       const void* __restrict__ pb,
                       unsigned short* __restrict__ caps,
                       const int* __restrict__ flagp) {
    int f = *flagp;
    int g = blockIdx.x * 256 + threadIdx.x;   // 256*1152
    int b = g / 1152, i = g - b * 1152;
    f32x4 h0 = *(const f32x4*)(h2t + (size_t)b * 9216 + i * 8);
    f32x4 h1 = *(const f32x4*)(h2t + (size_t)b * 9216 + i * 8 + 4);
    float h[8], ss = 0.f;
#pragma unroll
    for (int d = 0; d < 8; ++d) {
        int flat = i * 8 + d;
        int co = flat / 36;
        float v = clampf((d < 4 ? h0[d] : h1[d - 4]) + rdf(pb, co, f), 20000.f);
        h[d] = v;
        ss += v * v;
    }
    float sc = sqrtf(ss) / (1.f + ss);
    u16x8 cv;
#pragma unroll
    for (int d = 0; d < 8; ++d) cv[d] = f2bf(h[d] * sc);
    *(u16x8*)(caps + (size_t)g * 8) = cv;
}

// ---------------------------------------------------------------------------
// Routing pass: s-accumulate. grid (10 o, 36 i-tiles), block 256 (4 waves).
// W-tile (32 i x 128) in LDS, reused across all 256 images.
// cmode=0: c=1 (uniform, scale folded later). cmode=1: c=exp(a-M)*invS.
__global__ __launch_bounds__(256) void k_pass_s(
        const unsigned short* __restrict__ caps, const void* __restrict__ Wd,
        const float* __restrict__ a_buf, const float2* __restrict__ stats,
        float* __restrict__ s_sum, int cmode, const int* __restrict__ flagp) {
    __shared__ unsigned short Wl[4096];            // [32][128] bf16
    int f = *flagp;
    int o = blockIdx.x, i0 = blockIdx.y * 32;
    int tid = threadIdx.x;
    {
        int i = tid >> 3, seg = tid & 7;
        size_t base = ((size_t)(i0 + i) * 10 + o) * 128 + seg * 16;
        unsigned short* dst = Wl + i * 128 + seg * 16;
        if (f) {
            const float* wp = (const float*)Wd + base;
#pragma unroll
            for (int j = 0; j < 16; ++j) dst[j] = f2bf(wp[j]);
        } else {
            const unsigned short* wp = (const unsigned short*)Wd + base;
#pragma unroll
            for (int j = 0; j < 16; ++j) dst[j] = wp[j];
        }
    }
    __syncthreads();
    int wave = tid >> 6, lane = tid & 63;
    int n = lane & 15, ig = lane >> 4;
    for (int b = wave; b < 256; b += 4) {
        float2 st = cmode ? stats[b * 10 + o] : (float2){0.f, 0.f};
        const float* ab = a_buf + (size_t)(b * 10 + o) * 1152 + i0;
        float sn = 0.f;
#pragma unroll
        for (int k = 0; k < 8; ++k) {
            int i = ig + 4 * k;
            u16x8 cq = *(const u16x8*)(caps + (size_t)(b * 1152 + i0 + i) * 8);
            u16x8 wq = *(const u16x8*)(Wl + i * 128 + n * 8);
            float u = 0.f;
#pragma unroll
            for (int d = 0; d < 8; ++d) u += bf2f(wq[d]) * bf2f(cq[d]);
            float c = cmode ? (__expf(ab[i] - st.x) * st.y) : 1.f;
            sn += c * u;
        }
        sn += __shfl_down(sn, 32);
        sn += __shfl_down(sn, 16);
        if (lane < 16) atomicAdd(&s_sum[(size_t)(b * 10 + o) * 16 + n], sn);
    }
}

// Routing pass: dot (logit update). a[b,o,i] (addmode? += : =) v . u_i
__global__ __launch_bounds__(256) void k_pass_dot(
        const unsigned short* __restrict__ caps, const void* __restrict__ Wd,
        const float* __restrict__ v_buf, float* __restrict__ a_buf,
        int addmode, const int* __restrict__ flagp) {
    __shared__ unsigned short Wl[4096];
    int f = *flagp;
    int o = blockIdx.x, i0 = blockIdx.y * 32;
    int tid = threadIdx.x;
    {
        int i = tid >> 3, seg = tid & 7;
        size_t base = ((size_t)(i0 + i) * 10 + o) * 128 + seg * 16;
        unsigned short* dst = Wl + i * 128 + seg * 16;
        if (f) {
            const float* wp = (const float*)Wd + base;
#pragma unroll
            for (int j = 0; j < 16; ++j) dst[j] = f2bf(wp[j]);
        } else {
            const unsigned short* wp = (const unsigned short*)Wd + base;
#pragma unroll
            for (int j = 0; j < 16; ++j) dst[j] = wp[j];
        }
    }
    __syncthreads();
    int wave = tid >> 6, lane = tid & 63;
    int iloc = lane & 31, half = lane >> 5;
    for (int b = wave; b < 256; b += 4) {
        const float* vv = v_buf + (size_t)(b * 10 + o) * 16;
        float wv0 = 0.f, wv1 = 0.f, wv2 = 0.f, wv3 = 0.f;
#pragma unroll
        for (int nn = 0; nn < 16; ++nn) {
            u16x8 wq = *(const u16x8*)(Wl + iloc * 128 + nn * 8);
            float vn = vv[nn];
            wv0 += vn * bf2f(wq[half * 4 + 0]);
            wv1 += vn * bf2f(wq[half * 4 + 1]);
            wv2 += vn * bf2f(wq[half * 4 + 2]);
            wv3 += vn * bf2f(wq[half * 4 + 3]);
        }
        u16x8 cq = *(const u16x8*)(caps + (size_t)(b * 1152 + i0 + iloc) * 8);
        float dot = wv0 * bf2f(cq[half * 4 + 0]) + wv1 * bf2f(cq[half * 4 + 1]) +
                    wv2 * bf2f(cq[half * 4 + 2]) + wv3 * bf2f(cq[half * 4 + 3]);
        dot += __shfl_xor(dot, 32);
        if (lane < 32) {
            size_t idx = (size_t)(b * 10 + o) * 1152 + i0 + iloc;
            a_buf[idx] = addmode ? (a_buf[idx] + dot) : dot;
        }
    }
}

// softmax stats over i per (b,o): stats = {M, 1/S}
__global__ __launch_bounds__(256) void k_softmax(
        const float* __restrict__ a_buf, float2* __restrict__ stats) {
    __shared__ float red[4];
    int bo = blockIdx.x;
    int tid = threadIdx.x, wave = tid >> 6, lane = tid & 63;
    const float* ab = a_buf + (size_t)bo * 1152;
    float m = -3.0e38f;
#pragma unroll
    for (int c = 0; c < 5; ++c) {
        int i = tid + c * 256;
        if (i < 1152) m = fmaxf(m, ab[i]);
    }
#pragma unroll
    for (int off = 32; off; off >>= 1) m = fmaxf(m, __shfl_xor(m, off));
    if (lane == 0) red[wave] = m;
    __syncthreads();
    float M = fmaxf(fmaxf(red[0], red[1]), fmaxf(red[2], red[3]));
    float s = 0.f;
#pragma unroll
    for (int c = 0; c < 5; ++c) {
        int i = tid + c * 256;
        if (i < 1152) s += __expf(ab[i] - M);
    }
#pragma unroll
    for (int off = 32; off; off >>= 1) s += __shfl_xor(s, off);
    __syncthreads();
    if (lane == 0) red[wave] = s;
    __syncthreads();
    if (tid == 0) {
        float S = red[0] + red[1] + red[2] + red[3];
        stats[bo] = (float2){M, 1.f / S};
    }
}

// squash s_sum -> v_buf. scale1152: fold uniform 1/1152 (iter 1)
__global__ void k_squash(const float* __restrict__ s_sum,
                         float* __restrict__ v_buf, int scale1152) {
    int bo = blockIdx.x * 256 + threadIdx.x;      // 2560
    float sv[16], ss = 0.f;
    float sc0 = scale1152 ? (1.f / 1152.f) : 1.f;
#pragma unroll
    for (int nn = 0; nn < 16; ++nn) {
        float v = s_sum[(size_t)bo * 16 + nn] * sc0;
        sv[nn] = v;
        ss += v * v;
    }
    float sc = sqrtf(ss) / (1.f + ss);
#pragma unroll
    for (int nn = 0; nn < 16; ++nn) v_buf[(size_t)bo * 16 + nn] = sv[nn] * sc;
}

// final iteration: squash -> out v, vsel, one_hot
__global__ void k_final(const float* __restrict__ s_sum,
                        const int* __restrict__ label, void* __restrict__ d_out,
                        float* __restrict__ vsel, const int* __restrict__ flagp) {
    int f = *flagp;
    int bo = blockIdx.x * 256 + threadIdx.x;      // 2560
    int b = bo / 10, o = bo - b * 10;
    float sv[16], ss = 0.f;
#pragma unroll
    for (int nn = 0; nn < 16; ++nn) {
        float v = s_sum[(size_t)bo * 16 + nn];
        sv[nn] = v;
        ss += v * v;
    }
    float sc = sqrtf(ss) / (1.f + ss);
    int lbl = label[b];
#pragma unroll
    for (int nn = 0; nn < 16; ++nn) {
        float vn = clampf(sv[nn] * sc, 1.f);
        if (f) ((float*)d_out)[bo * 16 + nn] = vn;
        else   ((unsigned short*)d_out)[bo * 16 + nn] = f2bf(vn);
        if (o == lbl) vsel[b * 16 + nn] = vn;
    }
    float oh = (o == lbl) ? 1.f : 0.f;
    if (f) ((float*)d_out)[241664 + bo] = oh;
    else   ((unsigned short*)d_out)[241664 + bo] = f2bf(oh);
}

// ---------------------------------------------------------------------------
__global__ void k_dec1(const float* __restrict__ vsel, const int* __restrict__ label,
                       const void* __restrict__ w1, const void* __restrict__ b1,
                       float* __restrict__ r1, const int* __restrict__ flagp) {
    int f = *flagp;
    int b = blockIdx.x, j = threadIdx.x;   // 512 threads
    __shared__ float vs[16];
    if (j < 16) vs[j] = vsel[b * 16 + j];
    __syncthreads();
    int lbl = label[b];
    size_t wb = (size_t)j * 160 + lbl * 16;
    float acc = rdf(b1, j, f);
#pragma unroll
    for (int nn = 0; nn < 16; ++nn) acc += rdf(w1, wb + nn, f) * vs[nn];
    r1[b * 512 + j] = fmaxf(acc, 0.f);
}

// dec2: weight-stationary. grid 64 (16 out-neurons each), loop over batch.
__global__ __launch_bounds__(256) void k_dec2(
        const float* __restrict__ r1, const void* __restrict__ w2,
        const void* __restrict__ b2, float* __restrict__ r2,
        const int* __restrict__ flagp) {
    __shared__ unsigned short w2l[8192];           // [16][512] bf16
    int f = *flagp;
    int j0 = blockIdx.x * 16;
    int tid = threadIdx.x;
    for (int q = 0; q < 32; ++q) {
        int idx = tid * 32 + q;
        int j = idx >> 9, k = idx & 511;
        w2l[idx] = f2bf(rdf(w2, (size_t)(j0 + j) * 512 + k, f));
    }
    __syncthreads();
    int wave = tid >> 6, lane = tid & 63;
    int j = lane >> 2, seg = lane & 3;
    float bias = rdf(b2, j0 + j, f);
    for (int b = wave; b < 256; b += 4) {
        const float* rb = r1 + (size_t)b * 512 + seg * 128;
        const unsigned short* wb = w2l + j * 512 + seg * 128;
        float acc = 0.f;
#pragma unroll
        for (int k8 = 0; k8 < 16; ++k8) {
            u16x8 wq = *(const u16x8*)(wb + k8 * 8);
            f32x4 ra = *(const f32x4*)(rb + k8 * 8);
            f32x4 rc = *(const f32x4*)(rb + k8 * 8 + 4);
#pragma unroll
            for (int d = 0; d < 4; ++d) acc += bf2f(wq[d]) * ra[d];
#pragma unroll
            for (int d = 0; d < 4; ++d) acc += bf2f(wq[4 + d]) * rc[d];
        }
        acc += __shfl_xor(acc, 1);
        acc += __shfl_xor(acc, 2);
        if (seg == 0) r2[(size_t)b * 1024 + j0 + j] = fmaxf(acc + bias, 0.f);
    }
}

// dec3: weight-stationary. grid 49 (16 pixels each), loop over batch.
__global__ __launch_bounds__(256) void k_dec3(
        const float* __restrict__ r2, const void* __restrict__ w3,
        const void* __restrict__ b3, void* __restrict__ d_out,
        const int* __restrict__ flagp) {
    __shared__ unsigned short w3l[16384];          // [16][1024] bf16
    int f = *flagp;
    int p0 = blockIdx.x * 16;
    int tid = threadIdx.x;
    for (int q = 0; q < 64; ++q) {
        int idx = tid * 64 + q;
        int p = idx >> 10, k = idx & 1023;
        w3l[idx] = f2bf(rdf(w3, (size_t)(p0 + p) * 1024 + k, f));
    }
    __syncthreads();
    int wave = tid >> 6, lane = tid & 63;
    int p = lane >> 2, seg = lane & 3;
    float bias = rdf(b3, p0 + p, f);
    for (int b = wave; b < 256; b += 4) {
        const float* rb = r2 + (size_t)b * 1024 + seg * 256;
        const unsigned short* wb = w3l + p * 1024 + seg * 256;
        float acc = 0.f;
#pragma unroll
        for (int k8 = 0; k8 < 32; ++k8) {
            u16x8 wq = *(const u16x8*)(wb + k8 * 8);
            f32x4 ra = *(const f32x4*)(rb + k8 * 8);
            f32x4 rc = *(const f32x4*)(rb + k8 * 8 + 4);
#pragma unroll
            for (int d = 0; d < 4; ++d) acc += bf2f(wq[d]) * ra[d];
#pragma unroll
            for (int d = 0; d < 4; ++d) acc += bf2f(wq[4 + d]) * rc[d];
        }
        acc += __shfl_xor(acc, 1);
        acc += __shfl_xor(acc, 2);
        if (seg == 0) {
            float a = clampf(acc + bias, 60.f);
            float sig = 1.f / (1.f + __expf(-a));
            size_t oi = 40960 + (size_t)b * 784 + p0 + p;
            if (f) ((float*)d_out)[oi] = sig;
            else   ((unsigned short*)d_out)[oi] = f2bf(sig);
        }
    }
}

// ---------------------------------------------------------------------------
extern "C" void kernel_launch(void* const* d_in, const int* in_sizes, int n_in,
                              void* d_out, int out_size, void* d_ws, size_t ws_size,
                              hipStream_t stream) {
    const void* x    = d_in[0];
    const int*  lbl  = (const int*)d_in[1];
    const void* w1c  = d_in[2];
    const void* b1c  = d_in[3];
    const void* w2c  = d_in[4];
    const void* b2c  = d_in[5];
    const void* wdig = d_in[6];
    const void* dw1  = d_in[7];
    const void* db1  = d_in[8];
    const void* dw2  = d_in[9];
    const void* db2  = d_in[10];
    const void* dw3  = d_in[11];
    const void* db3  = d_in[12];
    (void)in_sizes; (void)n_in; (void)out_size; (void)ws_size;

    char* ws = (char*)d_ws;
    // ---- layout, total 72,532,224 B (ws_size >= 74.1 MB known from R4) ----
    int* flagp           = (int*)(ws);                        // 256
    float* h2t           = (float*)(ws + 256);                // 9,437,184
    unsigned short* Bp3  = (unsigned short*)(ws + 9437440);   // 10,616,832 [dead after conv2]
    //   overlays inside Bp3 region (all written after conv2):
    unsigned short* caps = (unsigned short*)(ws + 9437440);   // 4,718,592
    float* v_buf         = (float*)(ws + 14156032);           // 163,840
    float2* stats        = (float2*)(ws + 14340352);          // 20,480
    float* vsel          = (float*)(ws + 14360832);           // 16,384
    float* s_sums        = (float*)(ws + 14377216);           // 3 x 163,840
    float* s1s = s_sums, *s2s = s_sums + 40960, *s3s = s_sums + 81920;
    unsigned short* B1p  = (unsigned short*)(ws + 20054272);  // 49,152
    unsigned short* h1p  = (unsigned short*)(ws + 20103424);  // 52,428,800 [dead after conv2]
    //   overlays inside h1p region (written after conv2):
    float* a_buf         = (float*)(ws + 20103424);           // 11,796,480
    float* r1            = (float*)(ws + 31899904);           // 524,288
    float* r2            = (float*)(ws + 32424192);           // 1,048,576

    hipLaunchKernelGGL(k_detect,    dim3(1),    dim3(64),  0, stream, w1c, flagp);
    hipLaunchKernelGGL(k_zero,      dim3(2304), dim3(256), 0, stream, h2t);
    hipLaunchKernelGGL(k_repack_w1, dim3(96),   dim3(256), 0, stream, w1c, B1p, flagp);
    hipLaunchKernelGGL(k_repack_w2, dim3(256),  dim3(256), 0, stream, w2c, Bp3, flagp);

    hipLaunchKernelGGL(k_conv1, dim3(800, 2),   dim3(256), 0, stream, x, B1p, b1c, h1p, flagp);
    hipLaunchKernelGGL(k_conv2, dim3(72, 2, 8), dim3(256), 0, stream, h1p, Bp3, h2t);

    hipLaunchKernelGGL(k_zero,  dim3(120),  dim3(256), 0, stream, s_sums);
    hipLaunchKernelGGL(k_caps,  dim3(1152), dim3(256), 0, stream, h2t, b2c, caps, flagp);

    // routing: 3 iterations, W-stationary passes
    hipLaunchKernelGGL(k_pass_s,   dim3(10, 36), dim3(256), 0, stream,
                       caps, wdig, a_buf, stats, s1s, 0, flagp);
    hipLaunchKernelGGL(k_squash,   dim3(10),     dim3(256), 0, stream, s1s, v_buf, 1);
    hipLaunchKernelGGL(k_pass_dot, dim3(10, 36), dim3(256), 0, stream,
                       caps, wdig, v_buf, a_buf, 0, flagp);
    hipLaunchKernelGGL(k_softmax,  dim3(2560),   dim3(256), 0, stream, a_buf, stats);
    hipLaunchKernelGGL(k_pass_s,   dim3(10, 36), dim3(256), 0, stream,
                       caps, wdig, a_buf, stats, s2s, 1, flagp);
    hipLaunchKernelGGL(k_squash,   dim3(10),     dim3(256), 0, stream, s2s, v_buf, 0);
    hipLaunchKernelGGL(k_pass_dot, dim3(10, 36), dim3(256), 0, stream,
                       caps, wdig, v_buf, a_buf, 1, flagp);
    hipLaunchKernelGGL(k_softmax,  dim3(2560),   dim3(256), 0, stream, a_buf, stats);
    hipLaunchKernelGGL(k_pass_s,   dim3(10, 36), dim3(256), 0, stream,
                       caps, wdig, a_buf, stats, s3s, 1, flagp);
    hipLaunchKernelGGL(k_final,    dim3(10),     dim3(256), 0, stream,
                       s3s, lbl, d_out, vsel, flagp);

    hipLaunchKernelGGL(k_dec1, dim3(256), dim3(512), 0, stream, vsel, lbl, dw1, db1, r1, flagp);
    hipLaunchKernelGGL(k_dec2, dim3(64),  dim3(256), 0, stream, r1, dw2, db2, r2, flagp);
    hipLaunchKernelGGL(k_dec3, dim3(49),  dim3(256), 0, stream, r2, dw3, db3, d_out, flagp);
}

// Round 7
// 829.726 us; speedup vs baseline: 2.6203x; 2.6203x over previous
//
#include <hip/hip_runtime.h>
#include <hip/hip_bf16.h>
#include <stdint.h>

// ---------------------------------------------------------------------------
// CapsuleNet forward, MI355X gfx950.  Round 7 (R6 post-mortem: LDS staging
// had 16-way bank conflicts, transposed atomics 5x write amplification,
// multi-pass routing under-parallelized -> all reverted).
//  * conv2: R5 direct-global frags + 1-step register double-buffer prefetch.
//  * routing: R4 single-kernel, W_dig pre-repacked to bf16 [o][i][128].
//  * decoder: MFMA GEMMs on bf16 weights (cast once), r1/r2 bf16.
//  * ws 72.5 MB total; post-conv2 repacks overlay dead h1p region.
// ---------------------------------------------------------------------------

typedef short short8 __attribute__((ext_vector_type(8)));
typedef unsigned short u16x8 __attribute__((ext_vector_type(8)));
typedef float f32x4  __attribute__((ext_vector_type(4)));

__device__ inline float bf2f(unsigned short u) {
    unsigned int v = ((unsigned int)u) << 16;
    float f;
    __builtin_memcpy(&f, &v, 4);
    return f;
}
__device__ inline unsigned short f2bf(float f) {
    __hip_bfloat16 h = __float2bfloat16(f);
    unsigned short u;
    __builtin_memcpy(&u, &h, 2);
    return u;
}
__device__ inline float clampf(float x, float b) {   // scrubs NaN -> -b
    return fminf(fmaxf(x, -b), b);
}
__device__ inline float rdf(const void* p, size_t i, int f) {
    return f ? ((const float*)p)[i] : bf2f(((const unsigned short*)p)[i]);
}

// ---------------------------------------------------------------------------
__global__ void k_detect(const void* w, int* flag) {
    int lane = threadIdx.x;                       // 64 threads
    const unsigned short* u = (const unsigned short*)w;
    int cnt = 0;
#pragma unroll
    for (int j = 0; j < 4; ++j) {
        float v = fabsf(bf2f(u[lane * 4 + j]));
        if (v > 100.f) cnt++;
    }
#pragma unroll
    for (int off = 32; off; off >>= 1) cnt += __shfl_xor(cnt, off);
    if (lane == 0) flag[0] = (cnt >= 4) ? 1 : 0;
}

__global__ void k_zero(float* __restrict__ p) {    // grid*256 f32x4
    int i = blockIdx.x * 256 + threadIdx.x;
    ((f32x4*)p)[i] = (f32x4){0.f, 0.f, 0.f, 0.f};
}

// generic fp32/bf16 -> bf16 cast with zero-padding tail
__global__ void k_cast(const void* __restrict__ src, unsigned short* __restrict__ dst,
                       int n_valid, const int* __restrict__ flagp) {
    int f = *flagp;
    int i = blockIdx.x * 256 + threadIdx.x;
    dst[i] = (i < n_valid) ? f2bf(rdf(src, i, f)) : (unsigned short)0;
}

// W_dig [i][o][n][d] -> Wdb [o][i][128] bf16
__global__ void k_repack_wd(const void* __restrict__ wd, unsigned short* __restrict__ out,
                            const int* __restrict__ flagp) {
    int f = *flagp;
    int idx = blockIdx.x * 256 + threadIdx.x;     // 1,474,560
    int o = idx / 147456, rem = idx - o * 147456;
    int i = rem >> 7, nd = rem & 127;
    out[idx] = f2bf(rdf(wd, ((size_t)i * 10 + o) * 128 + nd, f));
}

// ---------------------------------------------------------------------------
__global__ void k_repack_w1(const void* __restrict__ w,
                            unsigned short* __restrict__ B1p,
                            const int* __restrict__ flagp) {
    int f = *flagp;
    int idx = blockIdx.x * 256 + threadIdx.x;      // 256*96
    int co = idx / 96, k = idx - co * 96;
    B1p[idx] = (k < 81) ? f2bf(rdf(w, (size_t)co * 81 + k, f)) : (unsigned short)0;
}

// pconv_w [co][ci][81] -> Bp2[t][co][ci] bf16 (R5 version: LDS transpose)
__global__ __launch_bounds__(256) void k_repack_w2(
        const void* __restrict__ w, unsigned short* __restrict__ Bp,
        const int* __restrict__ flagp) {
    __shared__ unsigned short wl[20736];           // [ci][t], 41.5 KB
    int f = *flagp;
    int co = blockIdx.x;
    int tid = threadIdx.x;
    size_t base = (size_t)co * 20736;
    for (int i = tid; i < 20736; i += 256)
        wl[i] = f2bf(rdf(w, base + i, f));         // wl[ci*81+t]
    __syncthreads();
    unsigned short* out = Bp + (co << 8) + tid;    // [t][co][ci=tid]
#pragma unroll 3
    for (int t = 0; t < 81; ++t)
        out[(size_t)t << 16] = wl[tid * 81 + t];
}

// ---------------------------------------------------------------------------
// conv1: C[102400,256] = im2col(x) * B1p^T, 128x128 tiles, x staged in LDS.
__global__ __launch_bounds__(256) void k_conv1(
        const void* __restrict__ x,
        const unsigned short* __restrict__ B1p,
        const void* __restrict__ bias,
        unsigned short* __restrict__ h1p,
        const int* __restrict__ flagp) {
    __shared__ unsigned short xl[1568];            // up to 2 images, bf16
    __shared__ int offt[96];
    int f = *flagp;
    int tid = threadIdx.x;
    if (tid < 96) offt[tid] = (tid < 81) ? (tid / 9) * 28 + (tid % 9) : 0;

    int mblk = blockIdx.x * 128;
    int bfirst = mblk / 400;
    int blast = (mblk + 127) / 400;
    int nload = (blast - bfirst + 1) * 784;
    for (int i = tid; i < nload; i += 256)
        xl[i] = f2bf(rdf(x, (size_t)bfirst * 784 + i, f));
    __syncthreads();

    int wave = tid >> 6, lane = tid & 63;
    int wr = wave >> 1, wc = wave & 1;
    int mbase = mblk + wr * 64;
    int nbase = blockIdx.y * 128 + wc * 64;
    int l15 = lane & 15, l4 = lane >> 4;

    int lbase[4];
#pragma unroll
    for (int mt = 0; mt < 4; ++mt) {
        int m = mbase + mt * 16 + l15;
        int img = m / 400 - bfirst, pos = m % 400;
        lbase[mt] = img * 784 + (pos / 20) * 28 + (pos % 20);
    }

    f32x4 acc[4][4];
#pragma unroll
    for (int mt = 0; mt < 4; ++mt)
#pragma unroll
        for (int nt = 0; nt < 4; ++nt)
            acc[mt][nt] = (f32x4){0.f, 0.f, 0.f, 0.f};

#pragma unroll
    for (int kc = 0; kc < 3; ++kc) {
        int kbase = kc * 32 + l4 * 8;
        short8 af[4], bfr[4];
#pragma unroll
        for (int mt = 0; mt < 4; ++mt)
#pragma unroll
            for (int j = 0; j < 8; ++j) {
                int k = kbase + j;
                af[mt][j] = (k < 81) ? (short)xl[lbase[mt] + offt[k]] : (short)0;
            }
#pragma unroll
        for (int nt = 0; nt < 4; ++nt)
            bfr[nt] = *(const short8*)(B1p + (size_t)(nbase + nt * 16 + l15) * 96 + kbase);
#pragma unroll
        for (int mt = 0; mt < 4; ++mt)
#pragma unroll
            for (int nt = 0; nt < 4; ++nt)
                acc[mt][nt] = __builtin_amdgcn_mfma_f32_16x16x32_bf16(
                    af[mt], bfr[nt], acc[mt][nt], 0, 0, 0);
    }

#pragma unroll
    for (int mt = 0; mt < 4; ++mt)
#pragma unroll
        for (int nt = 0; nt < 4; ++nt) {
            int col = nbase + nt * 16 + l15;
            float bv = rdf(bias, col, f);
#pragma unroll
            for (int r = 0; r < 4; ++r) {
                int row = mbase + mt * 16 + l4 * 4 + r;
                h1p[(size_t)row * 256 + col] = f2bf(clampf(acc[mt][nt][r] + bv, 1024.f));
            }
        }
}

// ---------------------------------------------------------------------------
// conv2: implicit im2col GEMM, 128x128 tiles (64x64 wave tiles), K-split S=8
// over taps, fp32 atomicAdd into h2f[row][col] (contiguous 64B segments).
// Register double-buffer: step k+1's 8 frag loads issued before step k's MFMAs.
__global__ __launch_bounds__(256) void k_conv2(
        const unsigned short* __restrict__ h1p,
        const unsigned short* __restrict__ Bp,
        float* __restrict__ h2f) {
    int tid = threadIdx.x;
    int wave = tid >> 6, lane = tid & 63;
    int wr = wave >> 1, wc = wave & 1;
    int mbase = blockIdx.x * 128 + wr * 64;
    int nbase = blockIdx.y * 128 + wc * 64;
    int s = blockIdx.z;
    int t0 = (81 * s) >> 3, t1 = (81 * (s + 1)) >> 3;
    int l15 = lane & 15, l4 = lane >> 4;
    int koff = l4 * 8;

    int rowoff[4];
#pragma unroll
    for (int mt = 0; mt < 4; ++mt) {
        int m = mbase + mt * 16 + l15;
        int bb = m / 36, pos = m - bb * 36;
        int y = pos / 6, xx = pos - y * 6;
        rowoff[mt] = (bb * 400 + y * 40 + xx * 2) * 256;   // (bb,2y,2x) NHWC
    }
    int brow[4];
#pragma unroll
    for (int nt = 0; nt < 4; ++nt) brow[nt] = (nt * 16 + l15) * 256;

    f32x4 acc[4][4];
#pragma unroll
    for (int mt = 0; mt < 4; ++mt)
#pragma unroll
        for (int nt = 0; nt < 4; ++nt)
            acc[mt][nt] = (f32x4){0.f, 0.f, 0.f, 0.f};

    short8 curA[4], curB[4];
    {   // prologue: load (t0, kc=0)
        int ky = t0 / 9, kx = t0 - ky * 9;
        int tadd = (ky * 20 + kx) * 256;
#pragma unroll
        for (int mt = 0; mt < 4; ++mt)
            curA[mt] = *(const short8*)(h1p + rowoff[mt] + tadd + koff);
        const unsigned short* bt = Bp + ((size_t)t0 << 16) + (size_t)nbase * 256;
#pragma unroll
        for (int nt = 0; nt < 4; ++nt)
            curB[nt] = *(const short8*)(bt + brow[nt] + koff);
    }

    for (int t = t0; t < t1; ++t) {
        int ky = t / 9, kx = t - ky * 9;
        int tadd = (ky * 20 + kx) * 256;
        int tn = t + 1;
        int kyn = tn / 9, kxn = tn - kyn * 9;
        int taddn = (kyn * 20 + kxn) * 256;
#pragma unroll
        for (int kc = 0; kc < 8; ++kc) {
            short8 nA[4], nB[4];
            bool last = (t == t1 - 1) && (kc == 7);
            int nkc = (kc + 1) & 7;
            int ntadd = (kc == 7) ? taddn : tadd;
            int ntt   = (kc == 7) ? tn : t;
            if (!last) {
                int ko = nkc * 32 + koff;
#pragma unroll
                for (int mt = 0; mt < 4; ++mt)
                    nA[mt] = *(const short8*)(h1p + rowoff[mt] + ntadd + ko);
                const unsigned short* bt = Bp + ((size_t)ntt << 16) + (size_t)nbase * 256;
#pragma unroll
                for (int nt = 0; nt < 4; ++nt)
                    nB[nt] = *(const short8*)(bt + brow[nt] + ko);
            }
#pragma unroll
            for (int mt = 0; mt < 4; ++mt)
#pragma unroll
                for (int nt = 0; nt < 4; ++nt)
                    acc[mt][nt] = __builtin_amdgcn_mfma_f32_16x16x32_bf16(
                        curA[mt], curB[nt], acc[mt][nt], 0, 0, 0);
            if (!last) {
#pragma unroll
                for (int mt = 0; mt < 4; ++mt) curA[mt] = nA[mt];
#pragma unroll
                for (int nt = 0; nt < 4; ++nt) curB[nt] = nB[nt];
            }
        }
    }

#pragma unroll
    for (int mt = 0; mt < 4; ++mt)
#pragma unroll
        for (int nt = 0; nt < 4; ++nt) {
            int col = nbase + nt * 16 + l15;
#pragma unroll
            for (int r = 0; r < 4; ++r) {
                int row = mbase + mt * 16 + l4 * 4 + r;
                atomicAdd(&h2f[(size_t)row * 256 + col], acc[mt][nt][r]);
            }
        }
}

// ---------------------------------------------------------------------------
// +bias, regroup [b][co][pos] into caps of 8, squash -> caps bf16
__global__ void k_caps(const float* __restrict__ h2f,
                       const void* __restrict__ pb,
                       unsigned short* __restrict__ caps,
                       const int* __restrict__ flagp) {
    int f = *flagp;
    int g = blockIdx.x * 256 + threadIdx.x;   // 256*1152
    int b = g / 1152, i = g - b * 1152;
    float h[8], ss = 0.f;
#pragma unroll
    for (int d = 0; d < 8; ++d) {
        int flat = i * 8 + d;                 // = co*36 + pos
        int co = flat / 36, pos = flat - co * 36;
        float v = clampf(h2f[(size_t)(b * 36 + pos) * 256 + co] + rdf(pb, co, f), 20000.f);
        h[d] = v;
        ss += v * v;
    }
    float sc = sqrtf(ss) / (1.f + ss);
    u16x8 cv;
#pragma unroll
    for (int d = 0; d < 8; ++d) cv[d] = f2bf(h[d] * sc);
    *(u16x8*)(caps + (size_t)g * 8) = cv;
}

// ---------------------------------------------------------------------------
// Dynamic routing. One block per (b,o). u[1152][16] in registers, 3 rows/thr.
// W read from bf16 Wdb [o][i][128] (L2-resident 2.95 MB).
__global__ __launch_bounds__(384) void k_routing(
        const unsigned short* __restrict__ caps, const unsigned short* __restrict__ Wdb,
        const int* __restrict__ label, void* __restrict__ d_out,
        float* __restrict__ vsel, const int* __restrict__ flagp) {
    int f = *flagp;
    int bo = blockIdx.x;
    int b = bo / 10, o = bo - b * 10;
    int tid = threadIdx.x;
    int wid = tid >> 6, lane = tid & 63;

    __shared__ float redw[6][16];
    __shared__ float sbuf[16];
    __shared__ float mred[8];
    __shared__ float sred[8];

    float u[3][16];
    float a[3] = {0.f, 0.f, 0.f};
    const unsigned short* capb = caps + (size_t)b * 9216;
    const unsigned short* wob = Wdb + (size_t)o * 147456;

#pragma unroll
    for (int r = 0; r < 3; ++r) {
        int i = tid + r * 384;                       // covers 0..1151 exactly
        u16x8 cq = *(const u16x8*)(capb + i * 8);
        float cf[8];
#pragma unroll
        for (int d = 0; d < 8; ++d) cf[d] = clampf(bf2f(cq[d]), 100.f);
        const u16x8* wq = (const u16x8*)(wob + (size_t)i * 128);
#pragma unroll
        for (int n = 0; n < 16; ++n) {
            u16x8 q = wq[n];
            float sacc = 0.f;
#pragma unroll
            for (int d = 0; d < 8; ++d) sacc += clampf(bf2f(q[d]), 1000.f) * cf[d];
            u[r][n] = clampf(sacc, 1.0e6f);
        }
    }

    for (int rr = 1; rr <= 3; ++rr) {
        float mx = fmaxf(fmaxf(a[0], a[1]), a[2]);
#pragma unroll
        for (int off = 32; off; off >>= 1) mx = fmaxf(mx, __shfl_xor(mx, off));
        if (lane == 0) mred[wid] = mx;
        __syncthreads();
        float M = mred[0];
#pragma unroll
        for (int w = 1; w < 6; ++w) M = fmaxf(M, mred[w]);

        float e[3], es = 0.f;
#pragma unroll
        for (int r = 0; r < 3; ++r) { e[r] = __expf(a[r] - M); es += e[r]; }
#pragma unroll
        for (int off = 32; off; off >>= 1) es += __shfl_xor(es, off);
        if (lane == 0) sred[wid] = es;
        __syncthreads();
        float S = 0.f;
#pragma unroll
        for (int w = 0; w < 6; ++w) S += sred[w];
        float inv = 1.f / S;

        float p[16];
#pragma unroll
        for (int n = 0; n < 16; ++n)
            p[n] = (e[0] * u[0][n] + e[1] * u[1][n] + e[2] * u[2][n]) * inv;
#pragma unroll
        for (int n = 0; n < 16; ++n)
#pragma unroll
            for (int off = 32; off; off >>= 1) p[n] += __shfl_xor(p[n], off);
        if (lane == 0)
#pragma unroll
            for (int n = 0; n < 16; ++n) redw[wid][n] = p[n];
        __syncthreads();
        if (tid < 16) {
            float sn = 0.f;
#pragma unroll
            for (int w = 0; w < 6; ++w) sn += redw[w][tid];
            sbuf[tid] = clampf(sn, 3.0e9f);
        }
        __syncthreads();

        float ss = 0.f;
#pragma unroll
        for (int n = 0; n < 16; ++n) ss += sbuf[n] * sbuf[n];
        float sc = sqrtf(ss) / (1.f + ss);

        if (rr < 3) {
#pragma unroll
            for (int r = 0; r < 3; ++r) {
                float dot = 0.f;
#pragma unroll
                for (int n = 0; n < 16; ++n) dot += sbuf[n] * u[r][n];
                a[r] += sc * dot;
            }
            __syncthreads();
        } else {
            int lbl = label[b];
            if (tid < 16) {
                float vn = clampf(sbuf[tid] * sc, 1.f);
                if (f) ((float*)d_out)[(bo << 4) + tid] = vn;
                else   ((unsigned short*)d_out)[(bo << 4) + tid] = f2bf(vn);
                if (o == lbl) vsel[(b << 4) + tid] = vn;
            }
            if (tid == 0) {
                float oh = (o == lbl) ? 1.f : 0.f;
                if (f) ((float*)d_out)[241664 + bo] = oh;
                else   ((unsigned short*)d_out)[241664 + bo] = f2bf(oh);
            }
        }
    }
}

// ---------------------------------------------------------------------------
// decoder layer 1 (K=16, masked): r1b bf16 [256][512]
__global__ void k_dec1(const float* __restrict__ vsel, const int* __restrict__ label,
                       const void* __restrict__ w1, const void* __restrict__ b1,
                       unsigned short* __restrict__ r1b, const int* __restrict__ flagp) {
    int f = *flagp;
    int b = blockIdx.x, j = threadIdx.x;   // 512 threads
    __shared__ float vs[16];
    if (j < 16) vs[j] = vsel[b * 16 + j];
    __syncthreads();
    int lbl = label[b];
    size_t wb = (size_t)j * 160 + lbl * 16;
    float acc = rdf(b1, j, f);
#pragma unroll
    for (int n = 0; n < 16; ++n) acc += rdf(w1, wb + n, f) * vs[n];
    r1b[b * 512 + j] = f2bf(fmaxf(acc, 0.f));
}

// decoder GEMM: C[256,N] = A[256,K] x B[N,K]^T (+bias, act). 128x128 tiles.
// mode 0: relu -> bf16 outb (stride ostride). mode 1: sigmoid -> d_out recon.
__global__ __launch_bounds__(256) void k_dgemm(
        const unsigned short* __restrict__ A, const unsigned short* __restrict__ B,
        const void* __restrict__ bias, int K, int mode, int nvalid, int ostride,
        unsigned short* __restrict__ outb, void* __restrict__ d_out,
        const int* __restrict__ flagp) {
    int f = *flagp;
    int tid = threadIdx.x;
    int wave = tid >> 6, lane = tid & 63;
    int wr = wave >> 1, wc = wave & 1;
    int mbase = blockIdx.x * 128 + wr * 64;
    int nbase = blockIdx.y * 128 + wc * 64;
    int l15 = lane & 15, l4 = lane >> 4;
    int koff = l4 * 8;

    f32x4 acc[4][4];
#pragma unroll
    for (int mt = 0; mt < 4; ++mt)
#pragma unroll
        for (int nt = 0; nt < 4; ++nt)
            acc[mt][nt] = (f32x4){0.f, 0.f, 0.f, 0.f};

    int nch = K >> 5;
    for (int kc = 0; kc < nch; ++kc) {
        int k0 = kc * 32 + koff;
        short8 af[4], bfr[4];
#pragma unroll
        for (int mt = 0; mt < 4; ++mt)
            af[mt] = *(const short8*)(A + (size_t)(mbase + mt * 16 + l15) * K + k0);
#pragma unroll
        for (int nt = 0; nt < 4; ++nt)
            bfr[nt] = *(const short8*)(B + (size_t)(nbase + nt * 16 + l15) * K + k0);
#pragma unroll
        for (int mt = 0; mt < 4; ++mt)
#pragma unroll
            for (int nt = 0; nt < 4; ++nt)
                acc[mt][nt] = __builtin_amdgcn_mfma_f32_16x16x32_bf16(
                    af[mt], bfr[nt], acc[mt][nt], 0, 0, 0);
    }

#pragma unroll
    for (int mt = 0; mt < 4; ++mt)
#pragma unroll
        for (int nt = 0; nt < 4; ++nt) {
            int col = nbase + nt * 16 + l15;
            float bv = (col < nvalid) ? rdf(bias, col, f) : 0.f;
#pragma unroll
            for (int r = 0; r < 4; ++r) {
                int row = mbase + mt * 16 + l4 * 4 + r;
                float v = acc[mt][nt][r] + bv;
                if (mode == 0) {
                    outb[(size_t)row * ostride + col] = f2bf(fmaxf(v, 0.f));
                } else if (col < nvalid) {
                    float a = clampf(v, 60.f);
                    float sig = 1.f / (1.f + __expf(-a));
                    size_t oi = 40960 + (size_t)row * 784 + col;
                    if (f) ((float*)d_out)[oi] = sig;
                    else   ((unsigned short*)d_out)[oi] = f2bf(sig);
                }
            }
        }
}

// ---------------------------------------------------------------------------
extern "C" void kernel_launch(void* const* d_in, const int* in_sizes, int n_in,
                              void* d_out, int out_size, void* d_ws, size_t ws_size,
                              hipStream_t stream) {
    const void* x    = d_in[0];
    const int*  lbl  = (const int*)d_in[1];
    const void* w1c  = d_in[2];
    const void* b1c  = d_in[3];
    const void* w2c  = d_in[4];
    const void* b2c  = d_in[5];
    const void* wdig = d_in[6];
    const void* dw1  = d_in[7];
    const void* db1  = d_in[8];
    const void* dw2  = d_in[9];
    const void* db2  = d_in[10];
    const void* dw3  = d_in[11];
    const void* db3  = d_in[12];
    (void)in_sizes; (void)n_in; (void)out_size; (void)ws_size;

    char* ws = (char*)d_ws;
    // ---- layout, total 72,532,224 B (ws_size >= 74,123,264 known from R4) --
    int* flagp           = (int*)(ws);                        // 256
    float* h2f           = (float*)(ws + 256);                // 9,437,184
    unsigned short* Bp2  = (unsigned short*)(ws + 9437440);   // 10,616,832 [dead after conv2]
    unsigned short* caps = (unsigned short*)(ws + 9437440);   //   overlay: 4,718,592
    unsigned short* B1p  = (unsigned short*)(ws + 20054272);  // 49,152
    unsigned short* h1p  = (unsigned short*)(ws + 20103424);  // 52,428,800 [dead after conv2]
    //   overlays inside h1p region (written after conv2):
    unsigned short* Wdb  = (unsigned short*)(ws + 20103424);  // 2,949,120
    unsigned short* w2b  = (unsigned short*)(ws + 23052544);  // 1,048,576
    unsigned short* w3b  = (unsigned short*)(ws + 24101120);  // 1,835,008
    unsigned short* r1b  = (unsigned short*)(ws + 25936128);  // 262,144
    unsigned short* r2b  = (unsigned short*)(ws + 26198272);  // 524,288
    float* vsel          = (float*)(ws + 26722560);           // 16,384

    hipLaunchKernelGGL(k_detect,    dim3(1),    dim3(64),  0, stream, w1c, flagp);
    hipLaunchKernelGGL(k_zero,      dim3(2304), dim3(256), 0, stream, h2f);
    hipLaunchKernelGGL(k_repack_w1, dim3(96),   dim3(256), 0, stream, w1c, B1p, flagp);
    hipLaunchKernelGGL(k_repack_w2, dim3(256),  dim3(256), 0, stream, w2c, Bp2, flagp);

    hipLaunchKernelGGL(k_conv1, dim3(800, 2),   dim3(256), 0, stream, x, B1p, b1c, h1p, flagp);
    hipLaunchKernelGGL(k_conv2, dim3(72, 2, 8), dim3(256), 0, stream, h1p, Bp2, h2f);

    // repacks into dead regions (stream-ordered after conv2)
    hipLaunchKernelGGL(k_repack_wd, dim3(5760), dim3(256), 0, stream, wdig, Wdb, flagp);
    hipLaunchKernelGGL(k_cast,      dim3(2048), dim3(256), 0, stream, dw2, w2b, 524288, flagp);
    hipLaunchKernelGGL(k_cast,      dim3(3584), dim3(256), 0, stream, dw3, w3b, 802816, flagp);

    hipLaunchKernelGGL(k_caps,    dim3(1152), dim3(256), 0, stream, h2f, b2c, caps, flagp);
    hipLaunchKernelGGL(k_routing, dim3(2560), dim3(384), 0, stream, caps, Wdb, lbl,
                       d_out, vsel, flagp);

    hipLaunchKernelGGL(k_dec1,  dim3(256),  dim3(512), 0, stream, vsel, lbl, dw1, db1, r1b, flagp);
    hipLaunchKernelGGL(k_dgemm, dim3(2, 8), dim3(256), 0, stream,
                       r1b, w2b, db2, 512, 0, 1024, 1024, r2b, d_out, flagp);
    hipLaunchKernelGGL(k_dgemm, dim3(2, 7), dim3(256), 0, stream,
                       r2b, w3b, db3, 1024, 1, 784, 0, (unsigned short*)nullptr, d_out, flagp);
}